// Round 4
// baseline (2066.614 us; speedup 1.0000x reference)
//
#include <hip/hip_runtime.h>
#include <hip/hip_bf16.h>
#include <math.h>

// Problem constants
#define B_    2
#define S_    4096
#define D_    768
#define H_    12
#define DH_   64
#define L_    2
#define W_    128
#define G_    1
#define DFF_  3072
#define NEG_  (-30000.0f)
#define NROWS (B_ * S_)      // 8192 token rows
#define NBLK  (S_ / W_)      // 32 blocks per sequence
#define ST5   (5 * D_)       // packed QKV5 row stride = 3840
#define QOFF  0
#define KOFF  (1 * D_)
#define VOFF  (2 * D_)
#define KGOFF (3 * D_)
#define VGOFF (4 * D_)

typedef __attribute__((ext_vector_type(8))) unsigned short bfrag;  // 8 bf16 = 4 VGPR
typedef __attribute__((ext_vector_type(4))) float f32x4;

__device__ __forceinline__ unsigned short f2bf(float f) {
  __hip_bfloat16 h = __float2bfloat16(f);
  return *reinterpret_cast<unsigned short*>(&h);
}

// ---------------- reduction helpers ----------------
__device__ __forceinline__ float wave_sum(float v) {
#pragma unroll
  for (int o = 32; o > 0; o >>= 1) v += __shfl_down(v, o, 64);
  return v;
}
__device__ __forceinline__ float wave_max(float v) {
#pragma unroll
  for (int o = 32; o > 0; o >>= 1) v = fmaxf(v, __shfl_down(v, o, 64));
  return v;
}
__device__ __forceinline__ float block_sum256(float v, float* sbuf) {
  v = wave_sum(v);
  int lane = threadIdx.x & 63, wid = threadIdx.x >> 6;
  if (lane == 0) sbuf[wid] = v;
  __syncthreads();
  float r = sbuf[0] + sbuf[1] + sbuf[2] + sbuf[3];
  __syncthreads();
  return r;
}

__device__ __forceinline__ float gelu_f(float x) {
  const float c = 0.7978845608028654f;  // sqrt(2/pi) -- jax approximate gelu
  float x3 = x * x * x;
  return 0.5f * x * (1.0f + tanhf(c * (x + 0.044715f * x3)));
}

// ---------------- embedding + layernorm (emits fp32 + bf16) ----------------
__global__ __launch_bounds__(256) void embed_ln_kernel(
    const int* __restrict__ inputx, const float* __restrict__ tok_emb,
    const float* __restrict__ pos_emb, const float* __restrict__ g,
    const float* __restrict__ bta, float* __restrict__ X,
    unsigned short* __restrict__ Xbf) {
  __shared__ float sbuf[4];
  int row = blockIdx.x;
  int s = row & (S_ - 1);
  int tok = inputx[row];
  const float* te = tok_emb + (size_t)tok * D_;
  const float* pe = pos_emb + (size_t)s * D_;
  float vals[3];
#pragma unroll
  for (int i = 0; i < 3; i++) {
    int d = threadIdx.x + i * 256;
    vals[i] = te[d] + pe[d];
  }
  float tot = block_sum256(vals[0] + vals[1] + vals[2], sbuf);
  float mu = tot * (1.0f / D_);
  float sq = 0.f;
#pragma unroll
  for (int i = 0; i < 3; i++) { float c = vals[i] - mu; sq += c * c; }
  float var = block_sum256(sq, sbuf) * (1.0f / D_);
  float rs = rsqrtf(var + 1e-5f);
  float* xr = X + (size_t)row * D_;
  unsigned short* xb = Xbf + (size_t)row * D_;
#pragma unroll
  for (int i = 0; i < 3; i++) {
    int d = threadIdx.x + i * 256;
    float v = (vals[i] - mu) * rs * g[d] + bta[d];
    xr[d] = v;
    xb[d] = f2bf(v);
  }
}

// ---------------- residual add + layernorm (in-place safe) ----------------
__global__ __launch_bounds__(256) void add_ln_kernel(
    const float* __restrict__ Xin, const float* __restrict__ T,
    const float* __restrict__ g, const float* __restrict__ bta,
    float* __restrict__ Xout, unsigned short* __restrict__ Xbf) {
  __shared__ float sbuf[4];
  int row = blockIdx.x;
  const float* xr = Xin + (size_t)row * D_;
  const float* tr = T + (size_t)row * D_;
  float vals[3];
#pragma unroll
  for (int i = 0; i < 3; i++) {
    int d = threadIdx.x + i * 256;
    vals[i] = xr[d] + tr[d];
  }
  float tot = block_sum256(vals[0] + vals[1] + vals[2], sbuf);
  float mu = tot * (1.0f / D_);
  float sq = 0.f;
#pragma unroll
  for (int i = 0; i < 3; i++) { float c = vals[i] - mu; sq += c * c; }
  float var = block_sum256(sq, sbuf) * (1.0f / D_);
  float rs = rsqrtf(var + 1e-5f);
  float* xo = Xout + (size_t)row * D_;
  unsigned short* xb = Xbf + (size_t)row * D_;
#pragma unroll
  for (int i = 0; i < 3; i++) {
    int d = threadIdx.x + i * 256;
    float v = (vals[i] - mu) * rs * g[d] + bta[d];
    xo[d] = v;
    xb[d] = f2bf(v);
  }
}

// ---------------- weight transpose + f32->bf16: WT[n][k] = bf(W[k][n]) ----------------
__global__ __launch_bounds__(256) void wtrans_kernel(
    const float* __restrict__ W, unsigned short* __restrict__ WT, int K, int N) {
  __shared__ float tile[32][33];
  int n0 = blockIdx.x * 32, k0 = blockIdx.y * 32;
  int tx = threadIdx.x & 31, ty = threadIdx.x >> 5;
#pragma unroll
  for (int i = 0; i < 4; i++) {
    int r = ty + i * 8;
    tile[r][tx] = W[(size_t)(k0 + r) * N + n0 + tx];
  }
  __syncthreads();
#pragma unroll
  for (int i = 0; i < 4; i++) {
    int r = ty + i * 8;
    WT[(size_t)(n0 + r) * K + k0 + tx] = f2bf(tile[tx][r]);
  }
}

// ---------------- bias pack: bias5[l][j] from 5 per-projection arrays ----------------
__global__ __launch_bounds__(256) void bias_pack_kernel(
    const float* __restrict__ bq, const float* __restrict__ bk,
    const float* __restrict__ bv, const float* __restrict__ bkg,
    const float* __restrict__ bvg, float* __restrict__ bias5) {
  int l = blockIdx.y;
  int j = blockIdx.x * 256 + threadIdx.x;
  if (j >= ST5) return;
  int which = j / D_, r = j - which * D_;
  float v;
  switch (which) {
    case 0: v = bq[l * D_ + r]; break;
    case 1: v = bk[l * D_ + r]; break;
    case 2: v = bv[l * D_ + r]; break;
    case 3: v = bkg[l * D_ + r]; break;
    default: v = bvg[l * D_ + r]; break;
  }
  bias5[(size_t)l * ST5 + j] = v;
}

// ---------------- bf16 MFMA GEMM: C = act(A @ BT^T + bias) ----------------
// A [M][K] bf16, BT [N][K] bf16 (pre-transposed weights). 128x128 tile, BK=32,
// 256 thr = 4 waves (2x2), each wave 64x64 = 4x4 frags of 16x16x32 MFMA.
// LDS tiles [128 rows][32 k] bf16, XOR-swizzled: byte ^= (row&7)<<4
// (linear upper-triangular GF(2) map -> bijective; write/read identical).
// Frag ds_read_b128: 8-row groups cover all 32 banks -> conflict-free;
// staging writes <=2-way (free, m136).
// mode 0: fp32 store. mode 1: gelu + bf16 store (FFN1).
__global__ __launch_bounds__(256) void gemm_bf16_kernel(
    const unsigned short* __restrict__ A, const unsigned short* __restrict__ BT,
    const float* __restrict__ bias, float* __restrict__ C,
    unsigned short* __restrict__ Cbf, int M, int N, int K, int mode) {
  __shared__ __align__(16) unsigned short As[128 * 32];
  __shared__ __align__(16) unsigned short Bs[128 * 32];
  const int m0 = blockIdx.y * 128, n0 = blockIdx.x * 128;
  const int t = threadIdx.x;
  const int w = t >> 6, l = t & 63;
  const int wm = w >> 1, wn = w & 1;
  const int lr = l & 15, lg = l >> 4;
  f32x4 acc[4][4] = {};
  for (int k0 = 0; k0 < K; k0 += 32) {
    __syncthreads();
#pragma unroll
    for (int i = 0; i < 2; i++) {
      int idx = t + i * 256;                 // 512 chunks of 16B per tile
      int row = idx >> 2, c = idx & 3;
      int ba = (row * 64 + c * 16) ^ ((row & 7) << 4);
      *reinterpret_cast<uint4*>(reinterpret_cast<char*>(As) + ba) =
          *reinterpret_cast<const uint4*>(&A[(size_t)(m0 + row) * K + k0 + c * 8]);
      *reinterpret_cast<uint4*>(reinterpret_cast<char*>(Bs) + ba) =
          *reinterpret_cast<const uint4*>(&BT[(size_t)(n0 + row) * K + k0 + c * 8]);
    }
    __syncthreads();
    bfrag af[4], bf[4];
#pragma unroll
    for (int f = 0; f < 4; f++) {
      int ra = wm * 64 + f * 16 + lr;
      af[f] = *reinterpret_cast<const bfrag*>(
          reinterpret_cast<const char*>(As) + ((ra * 64 + lg * 16) ^ ((ra & 7) << 4)));
      int rb = wn * 64 + f * 16 + lr;
      bf[f] = *reinterpret_cast<const bfrag*>(
          reinterpret_cast<const char*>(Bs) + ((rb * 64 + lg * 16) ^ ((rb & 7) << 4)));
    }
#pragma unroll
    for (int mi = 0; mi < 4; mi++)
#pragma unroll
      for (int ni = 0; ni < 4; ni++)
        asm volatile("v_mfma_f32_16x16x32_bf16 %0, %1, %2, %0"
                     : "+v"(acc[mi][ni])
                     : "v"(af[mi]), "v"(bf[ni]));
  }
  asm volatile("s_nop 7\n\ts_nop 7\n\ts_nop 7");  // MFMA->VALU read hazard
  // C/D layout (verified m89/m91): col = lane&15, row = (lane>>4)*4 + reg
#pragma unroll
  for (int ni = 0; ni < 4; ni++) {
    int col = n0 + wn * 64 + ni * 16 + lr;
    float bv = bias[col];
#pragma unroll
    for (int mi = 0; mi < 4; mi++) {
      int rowb = m0 + wm * 64 + mi * 16 + lg * 4;
#pragma unroll
      for (int j = 0; j < 4; j++) {
        float v = acc[mi][ni][j] + bv;
        if (mode == 1) {
          Cbf[(size_t)(rowb + j) * N + col] = f2bf(gelu_f(v));
        } else {
          C[(size_t)(rowb + j) * N + col] = v;
        }
      }
    }
  }
}

// ---------------- skinny matvec: out[b][j] = act((x_b @ W + bias) * scale) ----------------
__global__ __launch_bounds__(256) void skinny_kernel(
    const float* __restrict__ Xp, size_t xstride, const float* __restrict__ W,
    const float* __restrict__ bias, float* __restrict__ out, int K, int N,
    float scale, int dotanh) {
  __shared__ float red[4][64];
  int lane = threadIdx.x & 63, sl = threadIdx.x >> 6;
  int j = blockIdx.x * 64 + lane;
  int b = blockIdx.y;
  const float* x = Xp + (size_t)b * xstride;
  int kpt = K / 4;
  float s = 0.f;
  for (int k = sl * kpt; k < (sl + 1) * kpt; k++) s += x[k] * W[(size_t)k * N + j];
  red[sl][lane] = s;
  __syncthreads();
  if (sl == 0) {
    float v = (red[0][lane] + red[1][lane] + red[2][lane] + red[3][lane] +
               bias[j]) * scale;
    if (dotanh) v = tanhf(v);
    out[(size_t)b * N + j] = v;
  }
}

// ---------------- banded attention + global column (packed QKV5 in, bf16 out) ----------------
__global__ __launch_bounds__(128, 2) void banded_attn_kernel(
    const float* __restrict__ X5, const float* __restrict__ mask,
    unsigned short* __restrict__ Obf) {
  __shared__ float k_lds[64][64];
  __shared__ float v_lds[64][64];
  __shared__ float m_lds[64];
  int n = blockIdx.x, h = blockIdx.y, b = blockIdx.z;
  int qi = threadIdx.x;
  int s = n * W_ + qi;
  size_t qbase = ((size_t)(b * S_ + s)) * ST5 + QOFF + h * DH_;
  size_t obase = ((size_t)(b * S_ + s)) * D_ + h * DH_;

  float q[64];
#pragma unroll
  for (int i = 0; i < 16; i++) {
    float4 f = *reinterpret_cast<const float4*>(&X5[qbase + i * 4]);
    q[i * 4 + 0] = f.x * 0.125f;
    q[i * 4 + 1] = f.y * 0.125f;
    q[i * 4 + 2] = f.z * 0.125f;
    q[i * 4 + 3] = f.w * 0.125f;
  }

  float m = -1e30f, l = 0.f;
  float acc[64];
#pragma unroll
  for (int d = 0; d < 64; d++) acc[d] = 0.f;

  if (mask[(size_t)b * S_] > 0.f) {  // global column (kg/vg at pos 0)
    size_t gb = ((size_t)(b * S_)) * ST5 + h * DH_;
    const float* kgp = X5 + gb + KGOFF;
    const float* vgp = X5 + gb + VGOFF;
    float sc = 0.f;
#pragma unroll
    for (int d = 0; d < 64; d++) sc += q[d] * kgp[d];
    m = sc;
    l = 1.f;
#pragma unroll
    for (int d = 0; d < 64; d++) acc[d] = vgp[d];
  }

  for (int c = 0; c < 6; c++) {          // 6 chunks of 64 = 3W keys
    int kbase = (n - 1) * W_ + c * 64;
    __syncthreads();
    {
      int r = threadIdx.x & 63, hh = threadIdx.x >> 6;
      int kpos = kbase + r;
      bool inr = (kpos >= 0) && (kpos < S_);
      size_t kvb = ((size_t)(b * S_ + kpos)) * ST5 + h * DH_;
      const float* kp = X5 + kvb + KOFF;
      const float* vp = X5 + kvb + VOFF;
#pragma unroll
      for (int i = 0; i < 8; i++) {
        int cc = hh * 32 + i * 4;
        float4 kf = inr ? *reinterpret_cast<const float4*>(kp + cc)
                        : make_float4(0.f, 0.f, 0.f, 0.f);
        float4 vf = inr ? *reinterpret_cast<const float4*>(vp + cc)
                        : make_float4(0.f, 0.f, 0.f, 0.f);
        *reinterpret_cast<float4*>(&k_lds[r][cc]) = kf;
        *reinterpret_cast<float4*>(&v_lds[r][cc]) = vf;
      }
      if (hh == 0) m_lds[r] = inr ? mask[(size_t)b * S_ + kpos] : 0.f;
    }
    __syncthreads();
    for (int j = 0; j < 64; j++) {
      int ki = c * 64 + j;
      int kpos = kbase + j;
      bool valid = (ki >= qi) && (ki <= qi + 2 * W_) && (kpos >= G_) &&
                   (kpos < S_) && (m_lds[j] > 0.f);
      if (!valid) continue;
      float sc = 0.f;
#pragma unroll
      for (int d = 0; d < 64; d++) sc += q[d] * k_lds[j][d];
      float p;
      if (sc > m) {
        float r = expf(m - sc);
        l *= r;
#pragma unroll
        for (int d = 0; d < 64; d++) acc[d] *= r;
        m = sc;
        p = 1.f;
      } else {
        p = expf(sc - m);
      }
      l += p;
#pragma unroll
      for (int d = 0; d < 64; d++) acc[d] += p * v_lds[j][d];
    }
  }
  float inv = 1.f / l;
#pragma unroll
  for (int i = 0; i < 16; i++) {
    ushort4 o;
    o.x = f2bf(acc[i * 4 + 0] * inv);
    o.y = f2bf(acc[i * 4 + 1] * inv);
    o.z = f2bf(acc[i * 4 + 2] * inv);
    o.w = f2bf(acc[i * 4 + 3] * inv);
    *reinterpret_cast<ushort4*>(&Obf[obase + i * 4]) = o;
  }
}

// ---------------- global-row full attention (overwrites O rows s<G, bf16) ----------------
// Pass 1: scores for all S (strided over 256 threads) + softmax.
// Pass 2: PV parallel over 4 waves (wave = 1024-key slice for d=lane), LDS combine.
__global__ __launch_bounds__(256) void global_attn_kernel(
    const float* __restrict__ QG0, const float* __restrict__ X5,
    const float* __restrict__ mask, unsigned short* __restrict__ Obf) {
  __shared__ float sc[S_];
  __shared__ float qv[64];
  __shared__ float red[4];
  __shared__ float opart[4][64];
  int h = blockIdx.x, b = blockIdx.y;
  int t = threadIdx.x;
  if (t < 64) qv[t] = QG0[b * D_ + h * DH_ + t];
  __syncthreads();
  float lmax = -1e30f;
  for (int s = t; s < S_; s += 256) {
    const float* kp = X5 + ((size_t)(b * S_ + s)) * ST5 + KGOFF + h * DH_;
    float d0 = 0.f;
#pragma unroll
    for (int d = 0; d < 64; d++) d0 += qv[d] * kp[d];
    float v = (mask[(size_t)b * S_ + s] > 0.f) ? d0 : NEG_;
    sc[s] = v;
    lmax = fmaxf(lmax, v);
  }
  lmax = wave_max(lmax);
  int lane = t & 63, wid = t >> 6;
  if (lane == 0) red[wid] = lmax;
  __syncthreads();
  float M = fmaxf(fmaxf(red[0], red[1]), fmaxf(red[2], red[3]));
  __syncthreads();
  float ls = 0.f;
  for (int s = t; s < S_; s += 256) {
    float e = expf(sc[s] - M);
    sc[s] = e;
    ls += e;
  }
  ls = wave_sum(ls);
  if (lane == 0) red[wid] = ls;
  __syncthreads();
  float L = red[0] + red[1] + red[2] + red[3];
  {
    float o = 0.f;
    int s0 = wid * (S_ / 4), s1 = s0 + (S_ / 4);
    const float* vgp = X5 + ((size_t)(b * S_)) * ST5 + VGOFF + h * DH_ + lane;
    for (int s = s0; s < s1; s++) o += sc[s] * vgp[(size_t)s * ST5];
    opart[wid][lane] = o;
  }
  __syncthreads();
  if (t < 64) {
    float o = opart[0][t] + opart[1][t] + opart[2][t] + opart[3][t];
    Obf[((size_t)(b * S_)) * D_ + h * DH_ + t] = f2bf(o / L);
  }
}

// ---------------- final logits + NLL loss ----------------
__global__ __launch_bounds__(256) void loss_kernel(
    const float* __restrict__ pooled, const float* __restrict__ Wfc,
    const float* __restrict__ bfc, const int* __restrict__ labels,
    float* __restrict__ out) {
  __shared__ float logits[4];
  int pair = threadIdx.x >> 6, lane = threadIdx.x & 63;
  int b = pair >> 1, c = pair & 1;
  float s = 0.f;
  for (int k = lane; k < D_; k += 64) s += pooled[b * D_ + k] * Wfc[k * 2 + c];
  s = wave_sum(s);
  if (lane == 0) logits[pair] = s + bfc[c];
  __syncthreads();
  if (threadIdx.x == 0) {
    float loss = 0.f;
    for (int bb = 0; bb < B_; bb++) {
      float l0 = logits[bb * 2], l1 = logits[bb * 2 + 1];
      float mm = fmaxf(l0, l1);
      float lse = mm + logf(expf(l0 - mm) + expf(l1 - mm));
      loss += -(logits[bb * 2 + labels[bb]] - lse);
    }
    out[0] = loss * (1.0f / B_);
  }
}

// ---------------- host launch ----------------
extern "C" void kernel_launch(void* const* d_in, const int* in_sizes, int n_in,
                              void* d_out, int out_size, void* d_ws,
                              size_t ws_size, hipStream_t stream) {
  const int* inputx = (const int*)d_in[0];
  const float* mask = (const float*)d_in[1];
  const int* labels = (const int*)d_in[2];
  const float* tok_emb = (const float*)d_in[3];
  const float* pos_emb = (const float*)d_in[4];
  const float* ln_emb_g = (const float*)d_in[5];
  const float* ln_emb_b = (const float*)d_in[6];
  const float* Wq = (const float*)d_in[7];
  const float* bq = (const float*)d_in[8];
  const float* Wk = (const float*)d_in[9];
  const float* bk = (const float*)d_in[10];
  const float* Wv = (const float*)d_in[11];
  const float* bv = (const float*)d_in[12];
  const float* Wqg = (const float*)d_in[13];
  const float* bqg = (const float*)d_in[14];
  const float* Wkg = (const float*)d_in[15];
  const float* bkg = (const float*)d_in[16];
  const float* Wvg = (const float*)d_in[17];
  const float* bvg = (const float*)d_in[18];
  const float* Wo = (const float*)d_in[19];
  const float* bo = (const float*)d_in[20];
  const float* ln1_g = (const float*)d_in[21];
  const float* ln1_b = (const float*)d_in[22];
  const float* W1 = (const float*)d_in[23];
  const float* b1 = (const float*)d_in[24];
  const float* W2 = (const float*)d_in[25];
  const float* b2 = (const float*)d_in[26];
  const float* ln2_g = (const float*)d_in[27];
  const float* ln2_b = (const float*)d_in[28];
  const float* Wp = (const float*)d_in[29];
  const float* bp = (const float*)d_in[30];
  const float* Wfc = (const float*)d_in[31];
  const float* bfc = (const float*)d_in[32];

  const size_t NB = (size_t)B_ * S_ * D_;   // 6,291,456
  const size_t NB5 = NB * 5;                // packed QKV5 floats
  float* ws = (float*)d_ws;
  float* X = ws;                 // fp32 residual stream
  float* QKV5 = X + NB;          // [8192][3840] packed Q|K|V|KG|VG
  float* Tb = QKV5 + NB5;        // fp32 sublayer output
  float* QG0 = Tb + NB;                    // B*D
  float* pooled = QG0 + (size_t)B_ * D_;   // B*D
  float* bias5 = pooled + (size_t)B_ * D_; // L*3840
  unsigned short* Xbf = (unsigned short*)(bias5 + (size_t)L_ * ST5);  // NB
  unsigned short* Obf = Xbf + NB;                                     // NB
  unsigned short* WTbf = Obf + NB;             // 16,515,072 shorts (weights^T bf16)
  unsigned short* Hbf = (unsigned short*)QKV5; // FFN intermediate (50.3MB < 125.8MB;
                                               // QKV5 dead after attn + Wo GEMM)

  const size_t DD = (size_t)D_ * D_;        // 589824
  const size_t DF = (size_t)D_ * DFF_;      // 2359296
  const size_t PLS = 6 * DD + 2 * DF;       // per-layer WT stride

  // weight transpose + bf16 convert. The 5 projection transposes at wt+i*DD
  // are contiguous == one [3840][768] B^T for the fused QKV5 GEMM.
  for (int l = 0; l < L_; l++) {
    unsigned short* wt = WTbf + l * PLS;
    wtrans_kernel<<<dim3(24, 24), 256, 0, stream>>>(Wq + l * DD, wt + 0 * DD, D_, D_);
    wtrans_kernel<<<dim3(24, 24), 256, 0, stream>>>(Wk + l * DD, wt + 1 * DD, D_, D_);
    wtrans_kernel<<<dim3(24, 24), 256, 0, stream>>>(Wv + l * DD, wt + 2 * DD, D_, D_);
    wtrans_kernel<<<dim3(24, 24), 256, 0, stream>>>(Wkg + l * DD, wt + 3 * DD, D_, D_);
    wtrans_kernel<<<dim3(24, 24), 256, 0, stream>>>(Wvg + l * DD, wt + 4 * DD, D_, D_);
    wtrans_kernel<<<dim3(24, 24), 256, 0, stream>>>(Wo + l * DD, wt + 5 * DD, D_, D_);
    wtrans_kernel<<<dim3(96, 24), 256, 0, stream>>>(W1 + l * DF, wt + 6 * DD, D_, DFF_);
    wtrans_kernel<<<dim3(24, 96), 256, 0, stream>>>(W2 + l * DF, wt + 6 * DD + DF, DFF_, D_);
  }
  bias_pack_kernel<<<dim3(15, L_), 256, 0, stream>>>(bq, bk, bv, bkg, bvg, bias5);

  embed_ln_kernel<<<NROWS, 256, 0, stream>>>(inputx, tok_emb, pos_emb, ln_emb_g,
                                             ln_emb_b, X, Xbf);

  dim3 qkv_g(ST5 / 128, NROWS / 128);   // (30,64) fused 5-projection GEMM
  dim3 gemm_g(D_ / 128, NROWS / 128);   // (6,64)
  dim3 ffn1_g(DFF_ / 128, NROWS / 128); // (24,64)
  dim3 attn_g(NBLK, H_, B_);
  dim3 gl_g(H_, B_);
  dim3 sk_g(D_ / 64, B_);

  for (int l = 0; l < L_; l++) {
    unsigned short* wt = WTbf + l * PLS;
    gemm_bf16_kernel<<<qkv_g, 256, 0, stream>>>(Xbf, wt, bias5 + (size_t)l * ST5,
                                                QKV5, nullptr, NROWS, ST5, D_, 0);
    skinny_kernel<<<sk_g, 256, 0, stream>>>(X, (size_t)S_ * D_, Wqg + l * DD,
                                            bqg + (size_t)l * D_, QG0, D_, D_,
                                            0.125f, 0);
    banded_attn_kernel<<<attn_g, W_, 0, stream>>>(QKV5, mask, Obf);
    global_attn_kernel<<<gl_g, 256, 0, stream>>>(QG0, QKV5, mask, Obf);
    gemm_bf16_kernel<<<gemm_g, 256, 0, stream>>>(Obf, wt + 5 * DD, bo + (size_t)l * D_,
                                                 Tb, nullptr, NROWS, D_, D_, 0);
    add_ln_kernel<<<NROWS, 256, 0, stream>>>(X, Tb, ln1_g + (size_t)l * D_,
                                             ln1_b + (size_t)l * D_, X, Xbf);
    gemm_bf16_kernel<<<ffn1_g, 256, 0, stream>>>(Xbf, wt + 6 * DD, b1 + (size_t)l * DFF_,
                                                 nullptr, Hbf, NROWS, DFF_, D_, 1);
    gemm_bf16_kernel<<<gemm_g, 256, 0, stream>>>(Hbf, wt + 6 * DD + DF,
                                                 b2 + (size_t)l * D_, Tb, nullptr,
                                                 NROWS, D_, DFF_, 0);
    add_ln_kernel<<<NROWS, 256, 0, stream>>>(X, Tb, ln2_g + (size_t)l * D_,
                                             ln2_b + (size_t)l * D_, X, Xbf);
  }
  skinny_kernel<<<sk_g, 256, 0, stream>>>(X, (size_t)S_ * D_, Wp, bp, pooled,
                                          D_, D_, 1.0f, 1);
  loss_kernel<<<1, 256, 0, stream>>>(pooled, Wfc, bfc, labels, (float*)d_out);
}

// Round 9
// 1848.164 us; speedup vs baseline: 1.1182x; 1.1182x over previous
//
#include <hip/hip_runtime.h>
#include <hip/hip_bf16.h>
#include <math.h>

// Problem constants
#define B_    2
#define S_    4096
#define D_    768
#define H_    12
#define DH_   64
#define L_    2
#define W_    128
#define G_    1
#define DFF_  3072
#define NEG_  (-30000.0f)
#define NROWS (B_ * S_)      // 8192 token rows
#define ST5   (5 * D_)       // packed QKV5 row stride = 3840
#define QOFF  0
#define KOFF  (1 * D_)
#define VOFF  (2 * D_)
#define KGOFF (3 * D_)
#define VGOFF (4 * D_)
#define QPB   64             // queries per banded-attn block
#define CHK   32             // keys per staged chunk

typedef __attribute__((ext_vector_type(8))) unsigned short bfrag;  // 8 bf16 = 4 VGPR
typedef __attribute__((ext_vector_type(4))) float f32x4;

__device__ __forceinline__ unsigned short f2bf(float f) {
  __hip_bfloat16 h = __float2bfloat16(f);
  return *reinterpret_cast<unsigned short*>(&h);
}

// global->LDS direct (16B/lane). Dest must be wave-uniform base + lane*16.
__device__ __forceinline__ void gload16(const void* g, void* l) {
  __builtin_amdgcn_global_load_lds(
      (const __attribute__((address_space(1))) unsigned int*)g,
      (__attribute__((address_space(3))) unsigned int*)l, 16, 0, 0);
}

// ---------------- reduction helpers ----------------
__device__ __forceinline__ float wave_sum(float v) {
#pragma unroll
  for (int o = 32; o > 0; o >>= 1) v += __shfl_down(v, o, 64);
  return v;
}
__device__ __forceinline__ float wave_max(float v) {
#pragma unroll
  for (int o = 32; o > 0; o >>= 1) v = fmaxf(v, __shfl_down(v, o, 64));
  return v;
}
__device__ __forceinline__ float block_sum256(float v, float* sbuf) {
  v = wave_sum(v);
  int lane = threadIdx.x & 63, wid = threadIdx.x >> 6;
  if (lane == 0) sbuf[wid] = v;
  __syncthreads();
  float r = sbuf[0] + sbuf[1] + sbuf[2] + sbuf[3];
  __syncthreads();
  return r;
}

__device__ __forceinline__ float gelu_f(float x) {
  const float c = 0.7978845608028654f;  // sqrt(2/pi) -- jax approximate gelu
  float x3 = x * x * x;
  return 0.5f * x * (1.0f + tanhf(c * (x + 0.044715f * x3)));
}

// ---------------- embedding + layernorm (emits fp32 + bf16) ----------------
__global__ __launch_bounds__(256) void embed_ln_kernel(
    const int* __restrict__ inputx, const float* __restrict__ tok_emb,
    const float* __restrict__ pos_emb, const float* __restrict__ g,
    const float* __restrict__ bta, float* __restrict__ X,
    unsigned short* __restrict__ Xbf) {
  __shared__ float sbuf[4];
  int row = blockIdx.x;
  int s = row & (S_ - 1);
  int tok = inputx[row];
  const float* te = tok_emb + (size_t)tok * D_;
  const float* pe = pos_emb + (size_t)s * D_;
  float vals[3];
#pragma unroll
  for (int i = 0; i < 3; i++) {
    int d = threadIdx.x + i * 256;
    vals[i] = te[d] + pe[d];
  }
  float tot = block_sum256(vals[0] + vals[1] + vals[2], sbuf);
  float mu = tot * (1.0f / D_);
  float sq = 0.f;
#pragma unroll
  for (int i = 0; i < 3; i++) { float c = vals[i] - mu; sq += c * c; }
  float var = block_sum256(sq, sbuf) * (1.0f / D_);
  float rs = rsqrtf(var + 1e-5f);
  float* xr = X + (size_t)row * D_;
  unsigned short* xb = Xbf + (size_t)row * D_;
#pragma unroll
  for (int i = 0; i < 3; i++) {
    int d = threadIdx.x + i * 256;
    float v = (vals[i] - mu) * rs * g[d] + bta[d];
    xr[d] = v;
    xb[d] = f2bf(v);
  }
}

// ---------------- residual add + layernorm (in-place safe) ----------------
__global__ __launch_bounds__(256) void add_ln_kernel(
    const float* __restrict__ Xin, const float* __restrict__ T,
    const float* __restrict__ g, const float* __restrict__ bta,
    float* __restrict__ Xout, unsigned short* __restrict__ Xbf) {
  __shared__ float sbuf[4];
  int row = blockIdx.x;
  const float* xr = Xin + (size_t)row * D_;
  const float* tr = T + (size_t)row * D_;
  float vals[3];
#pragma unroll
  for (int i = 0; i < 3; i++) {
    int d = threadIdx.x + i * 256;
    vals[i] = xr[d] + tr[d];
  }
  float tot = block_sum256(vals[0] + vals[1] + vals[2], sbuf);
  float mu = tot * (1.0f / D_);
  float sq = 0.f;
#pragma unroll
  for (int i = 0; i < 3; i++) { float c = vals[i] - mu; sq += c * c; }
  float var = block_sum256(sq, sbuf) * (1.0f / D_);
  float rs = rsqrtf(var + 1e-5f);
  float* xo = Xout + (size_t)row * D_;
  unsigned short* xb = Xbf + (size_t)row * D_;
#pragma unroll
  for (int i = 0; i < 3; i++) {
    int d = threadIdx.x + i * 256;
    float v = (vals[i] - mu) * rs * g[d] + bta[d];
    xo[d] = v;
    xb[d] = f2bf(v);
  }
}

// ---------------- weight transpose + f32->bf16: WT[n][k] = bf(W[k][n]) ----------------
__global__ __launch_bounds__(256) void wtrans_kernel(
    const float* __restrict__ W, unsigned short* __restrict__ WT, int K, int N) {
  __shared__ float tile[32][33];
  int n0 = blockIdx.x * 32, k0 = blockIdx.y * 32;
  int tx = threadIdx.x & 31, ty = threadIdx.x >> 5;
#pragma unroll
  for (int i = 0; i < 4; i++) {
    int r = ty + i * 8;
    tile[r][tx] = W[(size_t)(k0 + r) * N + n0 + tx];
  }
  __syncthreads();
#pragma unroll
  for (int i = 0; i < 4; i++) {
    int r = ty + i * 8;
    WT[(size_t)(n0 + r) * K + k0 + tx] = f2bf(tile[tx][r]);
  }
}

// ---------------- bias pack: bias5[l][j] from 5 per-projection arrays ----------------
__global__ __launch_bounds__(256) void bias_pack_kernel(
    const float* __restrict__ bq, const float* __restrict__ bk,
    const float* __restrict__ bv, const float* __restrict__ bkg,
    const float* __restrict__ bvg, float* __restrict__ bias5) {
  int l = blockIdx.y;
  int j = blockIdx.x * 256 + threadIdx.x;
  if (j >= ST5) return;
  int which = j / D_, r = j - which * D_;
  float v;
  switch (which) {
    case 0: v = bq[l * D_ + r]; break;
    case 1: v = bk[l * D_ + r]; break;
    case 2: v = bv[l * D_ + r]; break;
    case 3: v = bkg[l * D_ + r]; break;
    default: v = bvg[l * D_ + r]; break;
  }
  bias5[(size_t)l * ST5 + j] = v;
}

// ---------------- bf16 MFMA GEMM: C = act(A @ BT^T + bias) ----------------
// m97 structure: 128x128 tile, BK=32, 4 waves (2x2), 4x4 frags of 16x16x32.
// Staging via global_load_lds width=16 into LINEAR [128][32] LDS (dest =
// wave-uniform base + lane*16: &As[(t+i*256)*8]). Frag ds_read_b128 from the
// 64B-stride rows covers all 32 banks at 8/bank = structural min (no swizzle
// needed at BK=32; the 32-way hazard only exists at >=128B row stride).
// mode 0: fp32 store. mode 1: gelu + bf16 store (FFN1).
__global__ __launch_bounds__(256) void gemm_bf16_kernel(
    const unsigned short* __restrict__ A, const unsigned short* __restrict__ BT,
    const float* __restrict__ bias, float* __restrict__ C,
    unsigned short* __restrict__ Cbf, int M, int N, int K, int mode) {
  __shared__ __align__(16) unsigned short As[128 * 32];
  __shared__ __align__(16) unsigned short Bs[128 * 32];
  const int m0 = blockIdx.y * 128, n0 = blockIdx.x * 128;
  const int t = threadIdx.x;
  const int w = t >> 6, l = t & 63;
  const int wm = w >> 1, wn = w & 1;
  const int lr = l & 15, lg = l >> 4;
  f32x4 acc[4][4] = {};
  for (int k0 = 0; k0 < K; k0 += 32) {
    __syncthreads();
#pragma unroll
    for (int i = 0; i < 2; i++) {
      int idx = t + i * 256;                 // 512 chunks of 16B per tile
      int row = idx >> 2, c = idx & 3;
      gload16(&A[(size_t)(m0 + row) * K + k0 + c * 8], &As[idx * 8]);
      gload16(&BT[(size_t)(n0 + row) * K + k0 + c * 8], &Bs[idx * 8]);
    }
    __syncthreads();
    bfrag af[4], bf[4];
#pragma unroll
    for (int f = 0; f < 4; f++) {
      int ra = wm * 64 + f * 16 + lr;
      af[f] = *reinterpret_cast<const bfrag*>(&As[ra * 32 + lg * 8]);
      int rb = wn * 64 + f * 16 + lr;
      bf[f] = *reinterpret_cast<const bfrag*>(&Bs[rb * 32 + lg * 8]);
    }
#pragma unroll
    for (int mi = 0; mi < 4; mi++)
#pragma unroll
      for (int ni = 0; ni < 4; ni++)
        asm volatile("v_mfma_f32_16x16x32_bf16 %0, %1, %2, %0"
                     : "+v"(acc[mi][ni])
                     : "v"(af[mi]), "v"(bf[ni]));
  }
  asm volatile("s_nop 7\n\ts_nop 7\n\ts_nop 7");  // MFMA->VALU read hazard
  // C/D layout (verified m89/m91): col = lane&15, row = (lane>>4)*4 + reg
#pragma unroll
  for (int ni = 0; ni < 4; ni++) {
    int col = n0 + wn * 64 + ni * 16 + lr;
    float bv = bias[col];
#pragma unroll
    for (int mi = 0; mi < 4; mi++) {
      int rowb = m0 + wm * 64 + mi * 16 + lg * 4;
#pragma unroll
      for (int j = 0; j < 4; j++) {
        float v = acc[mi][ni][j] + bv;
        if (mode == 1) {
          Cbf[(size_t)(rowb + j) * N + col] = f2bf(gelu_f(v));
        } else {
          C[(size_t)(rowb + j) * N + col] = v;
        }
      }
    }
  }
}

// ---------------- skinny matvec: out[b][j] = act((x_b @ W + bias) * scale) ----------------
__global__ __launch_bounds__(256) void skinny_kernel(
    const float* __restrict__ Xp, size_t xstride, const float* __restrict__ W,
    const float* __restrict__ bias, float* __restrict__ out, int K, int N,
    float scale, int dotanh) {
  __shared__ float red[4][64];
  int lane = threadIdx.x & 63, sl = threadIdx.x >> 6;
  int j = blockIdx.x * 64 + lane;
  int b = blockIdx.y;
  const float* x = Xp + (size_t)b * xstride;
  int kpt = K / 4;
  float s = 0.f;
  for (int k = sl * kpt; k < (sl + 1) * kpt; k++) s += x[k] * W[(size_t)k * N + j];
  red[sl][lane] = s;
  __syncthreads();
  if (sl == 0) {
    float v = (red[0][lane] + red[1][lane] + red[2][lane] + red[3][lane] +
               bias[j]) * scale;
    if (dotanh) v = tanhf(v);
    out[(size_t)b * N + j] = v;
  }
}

// ---------------- banded attention v2 + global column (bf16 out) ----------------
// grid (S/64, H, B), 256 threads. 64 queries/block; each query owned by a
// 4-lane quad (16 dims/lane); score combined via shfl_xor(1,2) -- bitwise
// identical across the quad (fp add commutative). K/V staged in 32-key LDS
// chunks with (row&7)<<4 XOR swizzle: staging writes hit the 8-access/bank
// structural min; inner-loop reads are 4-address multicast on disjoint bank
// groups (<=2-way, free). Each half-block needs only 10 of 12 chunks.
__global__ __launch_bounds__(256, 4) void banded_attn_kernel(
    const float* __restrict__ X5, const float* __restrict__ mask,
    unsigned short* __restrict__ Obf) {
  __shared__ __align__(16) float k_lds[CHK * 64];
  __shared__ __align__(16) float v_lds[CHK * 64];
  __shared__ float m_lds[CHK];
  int blk = blockIdx.x, h = blockIdx.y, b = blockIdx.z;
  int nb = blk >> 1, half = blk & 1;
  int t = threadIdx.x;
  int ql = t >> 2, slice = t & 3;
  int qi = half * 64 + ql;                  // index within W-block [0,128)
  int s = nb * W_ + qi;
  size_t rowb = (size_t)(b * S_ + s) * ST5 + h * DH_;

  float q[16];
#pragma unroll
  for (int i = 0; i < 4; i++) {
    float4 f = *reinterpret_cast<const float4*>(
        &X5[rowb + QOFF + slice * 16 + i * 4]);
    q[i * 4 + 0] = f.x * 0.125f;
    q[i * 4 + 1] = f.y * 0.125f;
    q[i * 4 + 2] = f.z * 0.125f;
    q[i * 4 + 3] = f.w * 0.125f;
  }

  float m = -1e30f, l = 0.f;
  float acc[16];
#pragma unroll
  for (int d = 0; d < 16; d++) acc[d] = 0.f;

  if (mask[(size_t)b * S_] > 0.f) {  // global column (kg/vg at pos 0)
    size_t gb = (size_t)(b * S_) * ST5 + h * DH_ + slice * 16;
    const float* kgp = X5 + gb + KGOFF;
    const float* vgp = X5 + gb + VGOFF;
    float sc = 0.f;
#pragma unroll
    for (int d = 0; d < 16; d++) sc += q[d] * kgp[d];
    sc += __shfl_xor(sc, 1);
    sc += __shfl_xor(sc, 2);
    m = sc;
    l = 1.f;
#pragma unroll
    for (int d = 0; d < 16; d++) acc[d] = vgp[d];
  }

  int c0 = half * 2;                        // chunk range: [c0, c0+10)
  for (int c = c0; c < c0 + 10; c++) {
    int kbase = (nb - 1) * W_ + c * CHK;
    __syncthreads();
#pragma unroll
    for (int i = 0; i < 2; i++) {
      int idx = t + i * 256;                // 512 float4s (k row-major)
      int kr = idx >> 4, c4 = idx & 15;
      int kpos = kbase + kr;
      bool inr = (kpos >= 0) && (kpos < S_);
      size_t kvb = (size_t)(b * S_ + kpos) * ST5 + h * DH_ + c4 * 4;
      float4 kf = inr ? *reinterpret_cast<const float4*>(&X5[kvb + KOFF])
                      : make_float4(0.f, 0.f, 0.f, 0.f);
      float4 vf = inr ? *reinterpret_cast<const float4*>(&X5[kvb + VOFF])
                      : make_float4(0.f, 0.f, 0.f, 0.f);
      int ba = (kr * 256 + c4 * 16) ^ ((kr & 7) << 4);
      *reinterpret_cast<float4*>(reinterpret_cast<char*>(k_lds) + ba) = kf;
      *reinterpret_cast<float4*>(reinterpret_cast<char*>(v_lds) + ba) = vf;
    }
    if (t < CHK) {
      int kpos = kbase + t;
      m_lds[t] = (kpos >= 0 && kpos < S_) ? mask[(size_t)b * S_ + kpos] : 0.f;
    }
    __syncthreads();
    for (int j = 0; j < CHK; j++) {
      int ki = c * CHK + j;
      int kpos = kbase + j;
      bool valid = (ki >= qi) && (ki <= qi + 2 * W_) && (kpos >= G_) &&
                   (kpos < S_) && (m_lds[j] > 0.f);
      if (!valid) continue;
      float sc = 0.f;
#pragma unroll
      for (int ii = 0; ii < 4; ii++) {
        int ba = (j * 256 + (slice * 4 + ii) * 16) ^ ((j & 7) << 4);
        float4 kf = *reinterpret_cast<const float4*>(
            reinterpret_cast<const char*>(k_lds) + ba);
        sc += q[ii * 4 + 0] * kf.x + q[ii * 4 + 1] * kf.y +
              q[ii * 4 + 2] * kf.z + q[ii * 4 + 3] * kf.w;
      }
      sc += __shfl_xor(sc, 1);
      sc += __shfl_xor(sc, 2);
      float p;
      if (sc > m) {
        float r = __expf(m - sc);
        l *= r;
#pragma unroll
        for (int d = 0; d < 16; d++) acc[d] *= r;
        m = sc;
        p = 1.f;
      } else {
        p = __expf(sc - m);
      }
      l += p;
#pragma unroll
      for (int ii = 0; ii < 4; ii++) {
        int ba = (j * 256 + (slice * 4 + ii) * 16) ^ ((j & 7) << 4);
        float4 vf = *reinterpret_cast<const float4*>(
            reinterpret_cast<const char*>(v_lds) + ba);
        acc[ii * 4 + 0] += p * vf.x;
        acc[ii * 4 + 1] += p * vf.y;
        acc[ii * 4 + 2] += p * vf.z;
        acc[ii * 4 + 3] += p * vf.w;
      }
    }
  }
  float inv = 1.f / l;
  size_t ob = (size_t)(b * S_ + s) * D_ + h * DH_ + slice * 16;
#pragma unroll
  for (int i = 0; i < 4; i++) {
    ushort4 o;
    o.x = f2bf(acc[i * 4 + 0] * inv);
    o.y = f2bf(acc[i * 4 + 1] * inv);
    o.z = f2bf(acc[i * 4 + 2] * inv);
    o.w = f2bf(acc[i * 4 + 3] * inv);
    *reinterpret_cast<ushort4*>(&Obf[ob + i * 4]) = o;
  }
}

// ---------------- global-row full attention (overwrites O rows s<G, bf16) ----------------
__global__ __launch_bounds__(256) void global_attn_kernel(
    const float* __restrict__ QG0, const float* __restrict__ X5,
    const float* __restrict__ mask, unsigned short* __restrict__ Obf) {
  __shared__ float sc[S_];
  __shared__ float qv[64];
  __shared__ float red[4];
  __shared__ float opart[4][64];
  int h = blockIdx.x, b = blockIdx.y;
  int t = threadIdx.x;
  if (t < 64) qv[t] = QG0[b * D_ + h * DH_ + t];
  __syncthreads();
  float lmax = -1e30f;
  for (int s = t; s < S_; s += 256) {
    const float* kp = X5 + ((size_t)(b * S_ + s)) * ST5 + KGOFF + h * DH_;
    float d0 = 0.f;
#pragma unroll
    for (int d = 0; d < 64; d++) d0 += qv[d] * kp[d];
    float v = (mask[(size_t)b * S_ + s] > 0.f) ? d0 : NEG_;
    sc[s] = v;
    lmax = fmaxf(lmax, v);
  }
  lmax = wave_max(lmax);
  int lane = t & 63, wid = t >> 6;
  if (lane == 0) red[wid] = lmax;
  __syncthreads();
  float M = fmaxf(fmaxf(red[0], red[1]), fmaxf(red[2], red[3]));
  __syncthreads();
  float ls = 0.f;
  for (int s = t; s < S_; s += 256) {
    float e = expf(sc[s] - M);
    sc[s] = e;
    ls += e;
  }
  ls = wave_sum(ls);
  if (lane == 0) red[wid] = ls;
  __syncthreads();
  float L = red[0] + red[1] + red[2] + red[3];
  {
    float o = 0.f;
    int s0 = wid * (S_ / 4), s1 = s0 + (S_ / 4);
    const float* vgp = X5 + ((size_t)(b * S_)) * ST5 + VGOFF + h * DH_ + lane;
    for (int s = s0; s < s1; s++) o += sc[s] * vgp[(size_t)s * ST5];
    opart[wid][lane] = o;
  }
  __syncthreads();
  if (t < 64) {
    float o = opart[0][t] + opart[1][t] + opart[2][t] + opart[3][t];
    Obf[((size_t)(b * S_)) * D_ + h * DH_ + t] = f2bf(o / L);
  }
}

// ---------------- final logits + NLL loss ----------------
__global__ __launch_bounds__(256) void loss_kernel(
    const float* __restrict__ pooled, const float* __restrict__ Wfc,
    const float* __restrict__ bfc, const int* __restrict__ labels,
    float* __restrict__ out) {
  __shared__ float logits[4];
  int pair = threadIdx.x >> 6, lane = threadIdx.x & 63;
  int b = pair >> 1, c = pair & 1;
  float s = 0.f;
  for (int k = lane; k < D_; k += 64) s += pooled[b * D_ + k] * Wfc[k * 2 + c];
  s = wave_sum(s);
  if (lane == 0) logits[pair] = s + bfc[c];
  __syncthreads();
  if (threadIdx.x == 0) {
    float loss = 0.f;
    for (int bb = 0; bb < B_; bb++) {
      float l0 = logits[bb * 2], l1 = logits[bb * 2 + 1];
      float mm = fmaxf(l0, l1);
      float lse = mm + logf(expf(l0 - mm) + expf(l1 - mm));
      loss += -(logits[bb * 2 + labels[bb]] - lse);
    }
    out[0] = loss * (1.0f / B_);
  }
}

// ---------------- host launch ----------------
extern "C" void kernel_launch(void* const* d_in, const int* in_sizes, int n_in,
                              void* d_out, int out_size, void* d_ws,
                              size_t ws_size, hipStream_t stream) {
  const int* inputx = (const int*)d_in[0];
  const float* mask = (const float*)d_in[1];
  const int* labels = (const int*)d_in[2];
  const float* tok_emb = (const float*)d_in[3];
  const float* pos_emb = (const float*)d_in[4];
  const float* ln_emb_g = (const float*)d_in[5];
  const float* ln_emb_b = (const float*)d_in[6];
  const float* Wq = (const float*)d_in[7];
  const float* bq = (const float*)d_in[8];
  const float* Wk = (const float*)d_in[9];
  const float* bk = (const float*)d_in[10];
  const float* Wv = (const float*)d_in[11];
  const float* bv = (const float*)d_in[12];
  const float* Wqg = (const float*)d_in[13];
  const float* bqg = (const float*)d_in[14];
  const float* Wkg = (const float*)d_in[15];
  const float* bkg = (const float*)d_in[16];
  const float* Wvg = (const float*)d_in[17];
  const float* bvg = (const float*)d_in[18];
  const float* Wo = (const float*)d_in[19];
  const float* bo = (const float*)d_in[20];
  const float* ln1_g = (const float*)d_in[21];
  const float* ln1_b = (const float*)d_in[22];
  const float* W1 = (const float*)d_in[23];
  const float* b1 = (const float*)d_in[24];
  const float* W2 = (const float*)d_in[25];
  const float* b2 = (const float*)d_in[26];
  const float* ln2_g = (const float*)d_in[27];
  const float* ln2_b = (const float*)d_in[28];
  const float* Wp = (const float*)d_in[29];
  const float* bp = (const float*)d_in[30];
  const float* Wfc = (const float*)d_in[31];
  const float* bfc = (const float*)d_in[32];

  const size_t NB = (size_t)B_ * S_ * D_;   // 6,291,456
  const size_t NB5 = NB * 5;                // packed QKV5 floats
  float* ws = (float*)d_ws;
  float* X = ws;                 // fp32 residual stream
  float* QKV5 = X + NB;          // [8192][3840] packed Q|K|V|KG|VG
  float* Tb = QKV5 + NB5;        // fp32 sublayer output
  float* QG0 = Tb + NB;                    // B*D
  float* pooled = QG0 + (size_t)B_ * D_;   // B*D
  float* bias5 = pooled + (size_t)B_ * D_; // L*3840
  unsigned short* Xbf = (unsigned short*)(bias5 + (size_t)L_ * ST5);  // NB
  unsigned short* Obf = Xbf + NB;                                     // NB
  unsigned short* WTbf = Obf + NB;             // 16,515,072 shorts (weights^T bf16)
  unsigned short* Hbf = (unsigned short*)QKV5; // FFN intermediate (50.3MB < 125.8MB;
                                               // QKV5 dead after attn + Wo GEMM)

  const size_t DD = (size_t)D_ * D_;        // 589824
  const size_t DF = (size_t)D_ * DFF_;      // 2359296
  const size_t PLS = 6 * DD + 2 * DF;       // per-layer WT stride

  // weight transpose + bf16 convert. The 5 projection transposes at wt+i*DD
  // are contiguous == one [3840][768] B^T for the fused QKV5 GEMM.
  for (int l = 0; l < L_; l++) {
    unsigned short* wt = WTbf + l * PLS;
    wtrans_kernel<<<dim3(24, 24), 256, 0, stream>>>(Wq + l * DD, wt + 0 * DD, D_, D_);
    wtrans_kernel<<<dim3(24, 24), 256, 0, stream>>>(Wk + l * DD, wt + 1 * DD, D_, D_);
    wtrans_kernel<<<dim3(24, 24), 256, 0, stream>>>(Wv + l * DD, wt + 2 * DD, D_, D_);
    wtrans_kernel<<<dim3(24, 24), 256, 0, stream>>>(Wkg + l * DD, wt + 3 * DD, D_, D_);
    wtrans_kernel<<<dim3(24, 24), 256, 0, stream>>>(Wvg + l * DD, wt + 4 * DD, D_, D_);
    wtrans_kernel<<<dim3(24, 24), 256, 0, stream>>>(Wo + l * DD, wt + 5 * DD, D_, D_);
    wtrans_kernel<<<dim3(96, 24), 256, 0, stream>>>(W1 + l * DF, wt + 6 * DD, D_, DFF_);
    wtrans_kernel<<<dim3(24, 96), 256, 0, stream>>>(W2 + l * DF, wt + 6 * DD + DF, DFF_, D_);
  }
  bias_pack_kernel<<<dim3(15, L_), 256, 0, stream>>>(bq, bk, bv, bkg, bvg, bias5);

  embed_ln_kernel<<<NROWS, 256, 0, stream>>>(inputx, tok_emb, pos_emb, ln_emb_g,
                                             ln_emb_b, X, Xbf);

  dim3 qkv_g(ST5 / 128, NROWS / 128);   // (30,64) fused 5-projection GEMM
  dim3 gemm_g(D_ / 128, NROWS / 128);   // (6,64)
  dim3 ffn1_g(DFF_ / 128, NROWS / 128); // (24,64)
  dim3 attn_g(S_ / QPB, H_, B_);        // (64,12,2)
  dim3 gl_g(H_, B_);
  dim3 sk_g(D_ / 64, B_);

  for (int l = 0; l < L_; l++) {
    unsigned short* wt = WTbf + l * PLS;
    gemm_bf16_kernel<<<qkv_g, 256, 0, stream>>>(Xbf, wt, bias5 + (size_t)l * ST5,
                                                QKV5, nullptr, NROWS, ST5, D_, 0);
    skinny_kernel<<<sk_g, 256, 0, stream>>>(X, (size_t)S_ * D_, Wqg + l * DD,
                                            bqg + (size_t)l * D_, QG0, D_, D_,
                                            0.125f, 0);
    banded_attn_kernel<<<attn_g, 256, 0, stream>>>(QKV5, mask, Obf);
    global_attn_kernel<<<gl_g, 256, 0, stream>>>(QG0, QKV5, mask, Obf);
    gemm_bf16_kernel<<<gemm_g, 256, 0, stream>>>(Obf, wt + 5 * DD, bo + (size_t)l * D_,
                                                 Tb, nullptr, NROWS, D_, D_, 0);
    add_ln_kernel<<<NROWS, 256, 0, stream>>>(X, Tb, ln1_g + (size_t)l * D_,
                                             ln1_b + (size_t)l * D_, X, Xbf);
    gemm_bf16_kernel<<<ffn1_g, 256, 0, stream>>>(Xbf, wt + 6 * DD, b1 + (size_t)l * DFF_,
                                                 nullptr, Hbf, NROWS, DFF_, D_, 1);
    gemm_bf16_kernel<<<gemm_g, 256, 0, stream>>>(Hbf, wt + 6 * DD + DF,
                                                 b2 + (size_t)l * D_, Tb, nullptr,
                                                 NROWS, D_, DFF_, 0);
    add_ln_kernel<<<NROWS, 256, 0, stream>>>(X, Tb, ln2_g + (size_t)l * D_,
                                             ln2_b + (size_t)l * D_, X, Xbf);
  }
  skinny_kernel<<<sk_g, 256, 0, stream>>>(X, (size_t)S_ * D_, Wp, bp, pooled,
                                          D_, D_, 1.0f, 1);
  loss_kernel<<<1, 256, 0, stream>>>(pooled, Wfc, bfc, labels, (float*)d_out);
}

// Round 10
// 1537.070 us; speedup vs baseline: 1.3445x; 1.2024x over previous
//
#include <hip/hip_runtime.h>
#include <hip/hip_bf16.h>
#include <math.h>

// Problem constants
#define B_    2
#define S_    4096
#define D_    768
#define H_    12
#define DH_   64
#define L_    2
#define W_    128
#define G_    1
#define DFF_  3072
#define NEG_  (-30000.0f)
#define NROWS (B_ * S_)      // 8192 token rows
#define ST5   (5 * D_)       // packed QKV5 row stride = 3840
#define QOFF  0
#define KOFF  (1 * D_)
#define VOFF  (2 * D_)
#define KGOFF (3 * D_)
#define VGOFF (4 * D_)
#define LDSW  68             // LDS row stride in shorts (136B: 2-way banks w/ b64)

typedef __attribute__((ext_vector_type(8))) unsigned short bfrag;  // 8 bf16 = 4 VGPR
typedef __attribute__((ext_vector_type(4))) unsigned short u16x4;
typedef __attribute__((ext_vector_type(4))) float f32x4;

__device__ __forceinline__ unsigned short f2bf(float f) {
  __hip_bfloat16 h = __float2bfloat16(f);
  return *reinterpret_cast<unsigned short*>(&h);
}

// global->LDS direct (16B/lane). Dest must be wave-uniform base + lane*16.
__device__ __forceinline__ void gload16(const void* g, void* l) {
  __builtin_amdgcn_global_load_lds(
      (const __attribute__((address_space(1))) unsigned int*)g,
      (__attribute__((address_space(3))) unsigned int*)l, 16, 0, 0);
}

// LDS fragment read: rows of LDSW shorts; frag f covers k=f*32..f*32+31;
// lane (lr,lg) elem (g=lg, j) <-> col f*32+lg*8+j. Two b64 reads (8B aligned).
__device__ __forceinline__ bfrag ldsfrag(const unsigned short* base, int row,
                                         int f, int lg) {
  const u16x4* p =
      reinterpret_cast<const u16x4*>(base + row * LDSW + f * 32 + lg * 8);
  u16x4 a = p[0], c = p[1];
  return __builtin_shufflevector(a, c, 0, 1, 2, 3, 4, 5, 6, 7);
}

// ---------------- reduction helpers ----------------
__device__ __forceinline__ float wave_sum(float v) {
#pragma unroll
  for (int o = 32; o > 0; o >>= 1) v += __shfl_down(v, o, 64);
  return v;
}
__device__ __forceinline__ float wave_max(float v) {
#pragma unroll
  for (int o = 32; o > 0; o >>= 1) v = fmaxf(v, __shfl_down(v, o, 64));
  return v;
}
__device__ __forceinline__ float block_sum256(float v, float* sbuf) {
  v = wave_sum(v);
  int lane = threadIdx.x & 63, wid = threadIdx.x >> 6;
  if (lane == 0) sbuf[wid] = v;
  __syncthreads();
  float r = sbuf[0] + sbuf[1] + sbuf[2] + sbuf[3];
  __syncthreads();
  return r;
}

__device__ __forceinline__ float gelu_f(float x) {
  const float c = 0.7978845608028654f;  // sqrt(2/pi) -- jax approximate gelu
  float x3 = x * x * x;
  return 0.5f * x * (1.0f + tanhf(c * (x + 0.044715f * x3)));
}

// ---------------- embedding + layernorm (emits fp32 + bf16) ----------------
__global__ __launch_bounds__(256) void embed_ln_kernel(
    const int* __restrict__ inputx, const float* __restrict__ tok_emb,
    const float* __restrict__ pos_emb, const float* __restrict__ g,
    const float* __restrict__ bta, float* __restrict__ X,
    unsigned short* __restrict__ Xbf) {
  __shared__ float sbuf[4];
  int row = blockIdx.x;
  int s = row & (S_ - 1);
  int tok = inputx[row];
  const float* te = tok_emb + (size_t)tok * D_;
  const float* pe = pos_emb + (size_t)s * D_;
  float vals[3];
#pragma unroll
  for (int i = 0; i < 3; i++) {
    int d = threadIdx.x + i * 256;
    vals[i] = te[d] + pe[d];
  }
  float tot = block_sum256(vals[0] + vals[1] + vals[2], sbuf);
  float mu = tot * (1.0f / D_);
  float sq = 0.f;
#pragma unroll
  for (int i = 0; i < 3; i++) { float c = vals[i] - mu; sq += c * c; }
  float var = block_sum256(sq, sbuf) * (1.0f / D_);
  float rs = rsqrtf(var + 1e-5f);
  float* xr = X + (size_t)row * D_;
  unsigned short* xb = Xbf + (size_t)row * D_;
#pragma unroll
  for (int i = 0; i < 3; i++) {
    int d = threadIdx.x + i * 256;
    float v = (vals[i] - mu) * rs * g[d] + bta[d];
    xr[d] = v;
    xb[d] = f2bf(v);
  }
}

// ---------------- residual add + layernorm (in-place safe) ----------------
__global__ __launch_bounds__(256) void add_ln_kernel(
    const float* __restrict__ Xin, const float* __restrict__ T,
    const float* __restrict__ g, const float* __restrict__ bta,
    float* __restrict__ Xout, unsigned short* __restrict__ Xbf) {
  __shared__ float sbuf[4];
  int row = blockIdx.x;
  const float* xr = Xin + (size_t)row * D_;
  const float* tr = T + (size_t)row * D_;
  float vals[3];
#pragma unroll
  for (int i = 0; i < 3; i++) {
    int d = threadIdx.x + i * 256;
    vals[i] = xr[d] + tr[d];
  }
  float tot = block_sum256(vals[0] + vals[1] + vals[2], sbuf);
  float mu = tot * (1.0f / D_);
  float sq = 0.f;
#pragma unroll
  for (int i = 0; i < 3; i++) { float c = vals[i] - mu; sq += c * c; }
  float var = block_sum256(sq, sbuf) * (1.0f / D_);
  float rs = rsqrtf(var + 1e-5f);
  float* xo = Xout + (size_t)row * D_;
  unsigned short* xb = Xbf + (size_t)row * D_;
#pragma unroll
  for (int i = 0; i < 3; i++) {
    int d = threadIdx.x + i * 256;
    float v = (vals[i] - mu) * rs * g[d] + bta[d];
    xo[d] = v;
    xb[d] = f2bf(v);
  }
}

// ---------------- weight transpose + f32->bf16: WT[n][k] = bf(W[k][n]) ----------------
__global__ __launch_bounds__(256) void wtrans_kernel(
    const float* __restrict__ W, unsigned short* __restrict__ WT, int K, int N) {
  __shared__ float tile[32][33];
  int n0 = blockIdx.x * 32, k0 = blockIdx.y * 32;
  int tx = threadIdx.x & 31, ty = threadIdx.x >> 5;
#pragma unroll
  for (int i = 0; i < 4; i++) {
    int r = ty + i * 8;
    tile[r][tx] = W[(size_t)(k0 + r) * N + n0 + tx];
  }
  __syncthreads();
#pragma unroll
  for (int i = 0; i < 4; i++) {
    int r = ty + i * 8;
    WT[(size_t)(n0 + r) * K + k0 + tx] = f2bf(tile[tx][r]);
  }
}

// ---------------- bias pack: bias5[l][j] from 5 per-projection arrays ----------------
__global__ __launch_bounds__(256) void bias_pack_kernel(
    const float* __restrict__ bq, const float* __restrict__ bk,
    const float* __restrict__ bv, const float* __restrict__ bkg,
    const float* __restrict__ bvg, float* __restrict__ bias5) {
  int l = blockIdx.y;
  int j = blockIdx.x * 256 + threadIdx.x;
  if (j >= ST5) return;
  int which = j / D_, r = j - which * D_;
  float v;
  switch (which) {
    case 0: v = bq[l * D_ + r]; break;
    case 1: v = bk[l * D_ + r]; break;
    case 2: v = bv[l * D_ + r]; break;
    case 3: v = bkg[l * D_ + r]; break;
    default: v = bvg[l * D_ + r]; break;
  }
  bias5[(size_t)l * ST5 + j] = v;
}

// ---------------- bf16 MFMA GEMM: C = act(A @ BT^T + bias) ----------------
// (unchanged from the round-9 PASSING kernel)
__global__ __launch_bounds__(256) void gemm_bf16_kernel(
    const unsigned short* __restrict__ A, const unsigned short* __restrict__ BT,
    const float* __restrict__ bias, float* __restrict__ C,
    unsigned short* __restrict__ Cbf, int M, int N, int K, int mode) {
  __shared__ __align__(16) unsigned short As[128 * 32];
  __shared__ __align__(16) unsigned short Bs[128 * 32];
  const int m0 = blockIdx.y * 128, n0 = blockIdx.x * 128;
  const int t = threadIdx.x;
  const int w = t >> 6, l = t & 63;
  const int wm = w >> 1, wn = w & 1;
  const int lr = l & 15, lg = l >> 4;
  f32x4 acc[4][4] = {};
  for (int k0 = 0; k0 < K; k0 += 32) {
    __syncthreads();
#pragma unroll
    for (int i = 0; i < 2; i++) {
      int idx = t + i * 256;                 // 512 chunks of 16B per tile
      int row = idx >> 2, c = idx & 3;
      gload16(&A[(size_t)(m0 + row) * K + k0 + c * 8], &As[idx * 8]);
      gload16(&BT[(size_t)(n0 + row) * K + k0 + c * 8], &Bs[idx * 8]);
    }
    __syncthreads();
    bfrag af[4], bf[4];
#pragma unroll
    for (int f = 0; f < 4; f++) {
      int ra = wm * 64 + f * 16 + lr;
      af[f] = *reinterpret_cast<const bfrag*>(&As[ra * 32 + lg * 8]);
      int rb = wn * 64 + f * 16 + lr;
      bf[f] = *reinterpret_cast<const bfrag*>(&Bs[rb * 32 + lg * 8]);
    }
#pragma unroll
    for (int mi = 0; mi < 4; mi++)
#pragma unroll
      for (int ni = 0; ni < 4; ni++)
        asm volatile("v_mfma_f32_16x16x32_bf16 %0, %1, %2, %0"
                     : "+v"(acc[mi][ni])
                     : "v"(af[mi]), "v"(bf[ni]));
  }
  asm volatile("s_nop 7\n\ts_nop 7\n\ts_nop 7");  // MFMA->VALU read hazard
  // C/D layout (verified m89/m91): col = lane&15, row = (lane>>4)*4 + reg
#pragma unroll
  for (int ni = 0; ni < 4; ni++) {
    int col = n0 + wn * 64 + ni * 16 + lr;
    float bv = bias[col];
#pragma unroll
    for (int mi = 0; mi < 4; mi++) {
      int rowb = m0 + wm * 64 + mi * 16 + lg * 4;
#pragma unroll
      for (int j = 0; j < 4; j++) {
        float v = acc[mi][ni][j] + bv;
        if (mode == 1) {
          Cbf[(size_t)(rowb + j) * N + col] = f2bf(gelu_f(v));
        } else {
          C[(size_t)(rowb + j) * N + col] = v;
        }
      }
    }
  }
}

// ---------------- skinny matvec: out[b][j] = act((x_b @ W + bias) * scale) ----------------
__global__ __launch_bounds__(256) void skinny_kernel(
    const float* __restrict__ Xp, size_t xstride, const float* __restrict__ W,
    const float* __restrict__ bias, float* __restrict__ out, int K, int N,
    float scale, int dotanh) {
  __shared__ float red[4][64];
  int lane = threadIdx.x & 63, sl = threadIdx.x >> 6;
  int j = blockIdx.x * 64 + lane;
  int b = blockIdx.y;
  const float* x = Xp + (size_t)b * xstride;
  int kpt = K / 4;
  float s = 0.f;
  for (int k = sl * kpt; k < (sl + 1) * kpt; k++) s += x[k] * W[(size_t)k * N + j];
  red[sl][lane] = s;
  __syncthreads();
  if (sl == 0) {
    float v = (red[0][lane] + red[1][lane] + red[2][lane] + red[3][lane] +
               bias[j]) * scale;
    if (dotanh) v = tanhf(v);
    out[(size_t)b * N + j] = v;
  }
}

// ---------------- banded attention v3: MFMA flash-style ----------------
// grid (128, H, B): block = 64 queries (nb=blk>>1, half=blk&1), 4 waves x 16 q.
// 6 chunk passes: cc=0 = global pseudo-chunk (kg at key 0, vg value, rest
// zero+masked); cc=1..5 = band chunks of 64 keys (cband = half+cc-1, exactly
// covering ki in [64*half, 64*half+320) = the band for these 64 queries).
// Per chunk/wave: 8 MFMA QK^T -> mask (explicit predicates; masked p == 0
// even when a whole chunk is invalid) -> online softmax (16-lane shfl_xor
// row-reduce; C-layout row=(lane>>4)*4+reg, col=lane&15 [verified m89/m91 +
// rounds 4/9 HW pass]) -> P to LDS bf16 -> 8 MFMA PV with V staged
// TRANSPOSED ([d][key]). Both MFMA operands always frag-read from LDS with
// the identical (g,j)->g*8+j formula, so the HW internal k-map cancels.
// LDS row stride 68 shorts (136B) + b64 frag reads: ~2-way banks (free).
__global__ __launch_bounds__(256) void banded_attn_mfma_kernel(
    const float* __restrict__ X5, const float* __restrict__ mask,
    unsigned short* __restrict__ Obf) {
  __shared__ __align__(16) unsigned short k_lds[64 * LDSW];
  __shared__ __align__(16) unsigned short vt_lds[64 * LDSW];
  __shared__ __align__(16) unsigned short q_lds[64 * LDSW];  // Q, then P
  __shared__ float m_lds[64];
  const int blk = blockIdx.x, h = blockIdx.y, b = blockIdx.z;
  const int nb = blk >> 1, half = blk & 1;
  const int t = threadIdx.x, w = t >> 6, l = t & 63;
  const int lr = l & 15, lg = l >> 4;
  const int qbase = half * 64 + w * 16;  // wave's query base within W-block
  const float maskG = mask[(size_t)b * S_];

  // ---- stage Q (scaled 1/sqrt(DH)) -> q_lds[64][LDSW]
  {
    int qr = t >> 2, dq = (t & 3) * 16;
    size_t src =
        (size_t)(b * S_ + nb * W_ + half * 64 + qr) * ST5 + QOFF + h * DH_;
#pragma unroll
    for (int i = 0; i < 4; i++) {
      int d0 = dq + i * 4;
      float4 f = *reinterpret_cast<const float4*>(&X5[src + d0]);
      u16x4 p;
      p[0] = f2bf(f.x * 0.125f);
      p[1] = f2bf(f.y * 0.125f);
      p[2] = f2bf(f.z * 0.125f);
      p[3] = f2bf(f.w * 0.125f);
      *reinterpret_cast<u16x4*>(&q_lds[qr * LDSW + d0]) = p;
    }
  }
  __syncthreads();
  bfrag qf[2];
#pragma unroll
  for (int f = 0; f < 2; f++) qf[f] = ldsfrag(q_lds, w * 16 + lr, f, lg);

  f32x4 o[4] = {};
  float mrun[4], lrun[4];
#pragma unroll
  for (int j = 0; j < 4; j++) { mrun[j] = -3.0e38f; lrun[j] = 0.f; }

  for (int cc = 0; cc < 6; cc++) {
    const bool isg = (cc == 0);
    const int cband = half + cc - 1;
    const int kbase = isg ? 0 : ((nb - 1) * W_ + cband * 64);
    __syncthreads();  // prior chunk's LDS reads done (incl. Q-frag reads)
    // ---- stage K [key][d] and V^T [d][key] (bf16), zeros where OOB
    {
      int key = t >> 2, dq = (t & 3) * 16;
      if (!isg) {
        int kpos = kbase + key;
        bool inr = (kpos >= 0) && (kpos < S_);
        size_t kvb = (size_t)(b * S_ + kpos) * ST5 + h * DH_;
#pragma unroll
        for (int i = 0; i < 4; i++) {
          int d0 = dq + i * 4;
          float4 kf4 = inr ? *reinterpret_cast<const float4*>(&X5[kvb + KOFF + d0])
                           : make_float4(0.f, 0.f, 0.f, 0.f);
          float4 vf4 = inr ? *reinterpret_cast<const float4*>(&X5[kvb + VOFF + d0])
                           : make_float4(0.f, 0.f, 0.f, 0.f);
          u16x4 kp;
          kp[0] = f2bf(kf4.x); kp[1] = f2bf(kf4.y);
          kp[2] = f2bf(kf4.z); kp[3] = f2bf(kf4.w);
          *reinterpret_cast<u16x4*>(&k_lds[key * LDSW + d0]) = kp;
          vt_lds[(d0 + 0) * LDSW + key] = f2bf(vf4.x);
          vt_lds[(d0 + 1) * LDSW + key] = f2bf(vf4.y);
          vt_lds[(d0 + 2) * LDSW + key] = f2bf(vf4.z);
          vt_lds[(d0 + 3) * LDSW + key] = f2bf(vf4.w);
        }
      } else {
        size_t gb = (size_t)(b * S_) * ST5 + h * DH_;
#pragma unroll
        for (int i = 0; i < 4; i++) {
          int d0 = dq + i * 4;
          float4 kf4 = (key == 0)
                           ? *reinterpret_cast<const float4*>(&X5[gb + KGOFF + d0])
                           : make_float4(0.f, 0.f, 0.f, 0.f);
          float4 vf4 = (key == 0)
                           ? *reinterpret_cast<const float4*>(&X5[gb + VGOFF + d0])
                           : make_float4(0.f, 0.f, 0.f, 0.f);
          u16x4 kp;
          kp[0] = f2bf(kf4.x); kp[1] = f2bf(kf4.y);
          kp[2] = f2bf(kf4.z); kp[3] = f2bf(kf4.w);
          *reinterpret_cast<u16x4*>(&k_lds[key * LDSW + d0]) = kp;
          vt_lds[(d0 + 0) * LDSW + key] = f2bf(vf4.x);
          vt_lds[(d0 + 1) * LDSW + key] = f2bf(vf4.y);
          vt_lds[(d0 + 2) * LDSW + key] = f2bf(vf4.z);
          vt_lds[(d0 + 3) * LDSW + key] = f2bf(vf4.w);
        }
      }
      if (t < 64) {
        int kpos = kbase + t;
        m_lds[t] = (!isg && kpos >= 0 && kpos < S_)
                       ? mask[(size_t)b * S_ + kpos] : 0.f;
      }
    }
    __syncthreads();
    // ---- QK^T: S[q 16][key 64], dependent-acc MFMAs separated by nt loop
    f32x4 s[4] = {};
#pragma unroll
    for (int f = 0; f < 2; f++)
#pragma unroll
      for (int nt = 0; nt < 4; nt++) {
        bfrag kf = ldsfrag(k_lds, nt * 16 + lr, f, lg);
        asm volatile("v_mfma_f32_16x16x32_bf16 %0, %1, %2, %0"
                     : "+v"(s[nt]) : "v"(qf[f]), "v"(kf));
      }
    asm volatile("s_nop 7\n\ts_nop 7\n\ts_nop 7");
    // ---- mask + online softmax (explicit predicates)
    float mnew[4];
#pragma unroll
    for (int j = 0; j < 4; j++) mnew[j] = mrun[j];
    unsigned okrow[4] = {0u, 0u, 0u, 0u};
#pragma unroll
    for (int nt = 0; nt < 4; nt++) {
      int keyl = nt * 16 + lr;
      bool okk;
      int ki;
      if (isg) {
        okk = (keyl == 0) && (maskG > 0.f);
        ki = 0;
      } else {
        int kpos = kbase + keyl;
        okk = (kpos >= G_) && (kpos < S_) && (m_lds[keyl] > 0.f);
        ki = cband * 64 + keyl;
      }
#pragma unroll
      for (int j = 0; j < 4; j++) {
        int qi = qbase + lg * 4 + j;
        bool ok = okk && (isg || ((ki >= qi) && (ki <= qi + 2 * W_)));
        if (ok) {
          mnew[j] = fmaxf(mnew[j], s[nt][j]);
          okrow[j] |= (1u << nt);
        }
      }
    }
#pragma unroll
    for (int j = 0; j < 4; j++) {
      float v = mnew[j];
      v = fmaxf(v, __shfl_xor(v, 1));
      v = fmaxf(v, __shfl_xor(v, 2));
      v = fmaxf(v, __shfl_xor(v, 4));
      v = fmaxf(v, __shfl_xor(v, 8));
      mnew[j] = v;
    }
    float fac[4], psum[4];
#pragma unroll
    for (int j = 0; j < 4; j++) {
      fac[j] = __expf(mrun[j] - mnew[j]);  // 0-0 -> 1; -3e38-real -> 0
      psum[j] = 0.f;
    }
#pragma unroll
    for (int nt = 0; nt < 4; nt++)
#pragma unroll
      for (int j = 0; j < 4; j++) {
        float p = ((okrow[j] >> nt) & 1u) ? __expf(s[nt][j] - mnew[j]) : 0.f;
        s[nt][j] = p;
        psum[j] += p;
      }
#pragma unroll
    for (int j = 0; j < 4; j++) {
      float v = psum[j];
      v += __shfl_xor(v, 1);
      v += __shfl_xor(v, 2);
      v += __shfl_xor(v, 4);
      v += __shfl_xor(v, 8);
      lrun[j] = lrun[j] * fac[j] + v;
      mrun[j] = mnew[j];
    }
#pragma unroll
    for (int nt = 0; nt < 4; nt++)
#pragma unroll
      for (int j = 0; j < 4; j++) o[nt][j] *= fac[j];
    // ---- write P (bf16) into q_lds (Q regs already live; region reusable)
#pragma unroll
    for (int nt = 0; nt < 4; nt++)
#pragma unroll
      for (int j = 0; j < 4; j++)
        q_lds[(w * 16 + lg * 4 + j) * LDSW + nt * 16 + lr] = f2bf(s[nt][j]);
    __syncthreads();  // P visible (cross-lane)
    // ---- PV: O[q 16][d 64] += P x V
    bfrag pf[2];
#pragma unroll
    for (int f = 0; f < 2; f++) pf[f] = ldsfrag(q_lds, w * 16 + lr, f, lg);
#pragma unroll
    for (int f = 0; f < 2; f++)
#pragma unroll
      for (int nt = 0; nt < 4; nt++) {
        bfrag vtf = ldsfrag(vt_lds, nt * 16 + lr, f, lg);
        asm volatile("v_mfma_f32_16x16x32_bf16 %0, %1, %2, %0"
                     : "+v"(o[nt]) : "v"(pf[f]), "v"(vtf));
      }
  }
  asm volatile("s_nop 7\n\ts_nop 7\n\ts_nop 7");
  // ---- epilogue: O / l -> bf16 (rows s<G overwritten later by global_attn)
#pragma unroll
  for (int nt = 0; nt < 4; nt++)
#pragma unroll
    for (int j = 0; j < 4; j++) {
      int srow = nb * W_ + qbase + lg * 4 + j;
      float val = o[nt][j] / lrun[j];
      Obf[(size_t)(b * S_ + srow) * D_ + h * DH_ + nt * 16 + lr] = f2bf(val);
    }
}

// ---------------- global-row full attention (overwrites O rows s<G, bf16) ----------------
__global__ __launch_bounds__(256) void global_attn_kernel(
    const float* __restrict__ QG0, const float* __restrict__ X5,
    const float* __restrict__ mask, unsigned short* __restrict__ Obf) {
  __shared__ float sc[S_];
  __shared__ float qv[64];
  __shared__ float red[4];
  __shared__ float opart[4][64];
  int h = blockIdx.x, b = blockIdx.y;
  int t = threadIdx.x;
  if (t < 64) qv[t] = QG0[b * D_ + h * DH_ + t];
  __syncthreads();
  float lmax = -1e30f;
  for (int s = t; s < S_; s += 256) {
    const float* kp = X5 + ((size_t)(b * S_ + s)) * ST5 + KGOFF + h * DH_;
    float d0 = 0.f;
#pragma unroll
    for (int d = 0; d < 64; d++) d0 += qv[d] * kp[d];
    float v = (mask[(size_t)b * S_ + s] > 0.f) ? d0 : NEG_;
    sc[s] = v;
    lmax = fmaxf(lmax, v);
  }
  lmax = wave_max(lmax);
  int lane = t & 63, wid = t >> 6;
  if (lane == 0) red[wid] = lmax;
  __syncthreads();
  float M = fmaxf(fmaxf(red[0], red[1]), fmaxf(red[2], red[3]));
  __syncthreads();
  float ls = 0.f;
  for (int s = t; s < S_; s += 256) {
    float e = expf(sc[s] - M);
    sc[s] = e;
    ls += e;
  }
  ls = wave_sum(ls);
  if (lane == 0) red[wid] = ls;
  __syncthreads();
  float L = red[0] + red[1] + red[2] + red[3];
  {
    float o = 0.f;
    int s0 = wid * (S_ / 4), s1 = s0 + (S_ / 4);
    const float* vgp = X5 + ((size_t)(b * S_)) * ST5 + VGOFF + h * DH_ + lane;
    for (int s = s0; s < s1; s++) o += sc[s] * vgp[(size_t)s * ST5];
    opart[wid][lane] = o;
  }
  __syncthreads();
  if (t < 64) {
    float o = opart[0][t] + opart[1][t] + opart[2][t] + opart[3][t];
    Obf[((size_t)(b * S_)) * D_ + h * DH_ + t] = f2bf(o / L);
  }
}

// ---------------- final logits + NLL loss ----------------
__global__ __launch_bounds__(256) void loss_kernel(
    const float* __restrict__ pooled, const float* __restrict__ Wfc,
    const float* __restrict__ bfc, const int* __restrict__ labels,
    float* __restrict__ out) {
  __shared__ float logits[4];
  int pair = threadIdx.x >> 6, lane = threadIdx.x & 63;
  int b = pair >> 1, c = pair & 1;
  float s = 0.f;
  for (int k = lane; k < D_; k += 64) s += pooled[b * D_ + k] * Wfc[k * 2 + c];
  s = wave_sum(s);
  if (lane == 0) logits[pair] = s + bfc[c];
  __syncthreads();
  if (threadIdx.x == 0) {
    float loss = 0.f;
    for (int bb = 0; bb < B_; bb++) {
      float l0 = logits[bb * 2], l1 = logits[bb * 2 + 1];
      float mm = fmaxf(l0, l1);
      float lse = mm + logf(expf(l0 - mm) + expf(l1 - mm));
      loss += -(logits[bb * 2 + labels[bb]] - lse);
    }
    out[0] = loss * (1.0f / B_);
  }
}

// ---------------- host launch ----------------
extern "C" void kernel_launch(void* const* d_in, const int* in_sizes, int n_in,
                              void* d_out, int out_size, void* d_ws,
                              size_t ws_size, hipStream_t stream) {
  const int* inputx = (const int*)d_in[0];
  const float* mask = (const float*)d_in[1];
  const int* labels = (const int*)d_in[2];
  const float* tok_emb = (const float*)d_in[3];
  const float* pos_emb = (const float*)d_in[4];
  const float* ln_emb_g = (const float*)d_in[5];
  const float* ln_emb_b = (const float*)d_in[6];
  const float* Wq = (const float*)d_in[7];
  const float* bq = (const float*)d_in[8];
  const float* Wk = (const float*)d_in[9];
  const float* bk = (const float*)d_in[10];
  const float* Wv = (const float*)d_in[11];
  const float* bv = (const float*)d_in[12];
  const float* Wqg = (const float*)d_in[13];
  const float* bqg = (const float*)d_in[14];
  const float* Wkg = (const float*)d_in[15];
  const float* bkg = (const float*)d_in[16];
  const float* Wvg = (const float*)d_in[17];
  const float* bvg = (const float*)d_in[18];
  const float* Wo = (const float*)d_in[19];
  const float* bo = (const float*)d_in[20];
  const float* ln1_g = (const float*)d_in[21];
  const float* ln1_b = (const float*)d_in[22];
  const float* W1 = (const float*)d_in[23];
  const float* b1 = (const float*)d_in[24];
  const float* W2 = (const float*)d_in[25];
  const float* b2 = (const float*)d_in[26];
  const float* ln2_g = (const float*)d_in[27];
  const float* ln2_b = (const float*)d_in[28];
  const float* Wp = (const float*)d_in[29];
  const float* bp = (const float*)d_in[30];
  const float* Wfc = (const float*)d_in[31];
  const float* bfc = (const float*)d_in[32];

  const size_t NB = (size_t)B_ * S_ * D_;   // 6,291,456
  const size_t NB5 = NB * 5;                // packed QKV5 floats
  float* ws = (float*)d_ws;
  float* X = ws;                 // fp32 residual stream
  float* QKV5 = X + NB;          // [8192][3840] packed Q|K|V|KG|VG
  float* Tb = QKV5 + NB5;        // fp32 sublayer output
  float* QG0 = Tb + NB;                    // B*D
  float* pooled = QG0 + (size_t)B_ * D_;   // B*D
  float* bias5 = pooled + (size_t)B_ * D_; // L*3840
  unsigned short* Xbf = (unsigned short*)(bias5 + (size_t)L_ * ST5);  // NB
  unsigned short* Obf = Xbf + NB;                                     // NB
  unsigned short* WTbf = Obf + NB;             // 16,515,072 shorts (weights^T bf16)
  unsigned short* Hbf = (unsigned short*)QKV5; // FFN intermediate (50.3MB < 125.8MB;
                                               // QKV5 dead after attn + Wo GEMM)

  const size_t DD = (size_t)D_ * D_;        // 589824
  const size_t DF = (size_t)D_ * DFF_;      // 2359296
  const size_t PLS = 6 * DD + 2 * DF;       // per-layer WT stride

  // weight transpose + bf16 convert. The 5 projection transposes at wt+i*DD
  // are contiguous == one [3840][768] B^T for the fused QKV5 GEMM.
  for (int l = 0; l < L_; l++) {
    unsigned short* wt = WTbf + l * PLS;
    wtrans_kernel<<<dim3(24, 24), 256, 0, stream>>>(Wq + l * DD, wt + 0 * DD, D_, D_);
    wtrans_kernel<<<dim3(24, 24), 256, 0, stream>>>(Wk + l * DD, wt + 1 * DD, D_, D_);
    wtrans_kernel<<<dim3(24, 24), 256, 0, stream>>>(Wv + l * DD, wt + 2 * DD, D_, D_);
    wtrans_kernel<<<dim3(24, 24), 256, 0, stream>>>(Wkg + l * DD, wt + 3 * DD, D_, D_);
    wtrans_kernel<<<dim3(24, 24), 256, 0, stream>>>(Wvg + l * DD, wt + 4 * DD, D_, D_);
    wtrans_kernel<<<dim3(24, 24), 256, 0, stream>>>(Wo + l * DD, wt + 5 * DD, D_, D_);
    wtrans_kernel<<<dim3(96, 24), 256, 0, stream>>>(W1 + l * DF, wt + 6 * DD, D_, DFF_);
    wtrans_kernel<<<dim3(24, 96), 256, 0, stream>>>(W2 + l * DF, wt + 6 * DD + DF, DFF_, D_);
  }
  bias_pack_kernel<<<dim3(15, L_), 256, 0, stream>>>(bq, bk, bv, bkg, bvg, bias5);

  embed_ln_kernel<<<NROWS, 256, 0, stream>>>(inputx, tok_emb, pos_emb, ln_emb_g,
                                             ln_emb_b, X, Xbf);

  dim3 qkv_g(ST5 / 128, NROWS / 128);   // (30,64) fused 5-projection GEMM
  dim3 gemm_g(D_ / 128, NROWS / 128);   // (6,64)
  dim3 ffn1_g(DFF_ / 128, NROWS / 128); // (24,64)
  dim3 attn_g(S_ / 64, H_, B_);         // (128,12,2) MFMA banded attention
  dim3 gl_g(H_, B_);
  dim3 sk_g(D_ / 64, B_);

  for (int l = 0; l < L_; l++) {
    unsigned short* wt = WTbf + l * PLS;
    gemm_bf16_kernel<<<qkv_g, 256, 0, stream>>>(Xbf, wt, bias5 + (size_t)l * ST5,
                                                QKV5, nullptr, NROWS, ST5, D_, 0);
    skinny_kernel<<<sk_g, 256, 0, stream>>>(X, (size_t)S_ * D_, Wqg + l * DD,
                                            bqg + (size_t)l * D_, QG0, D_, D_,
                                            0.125f, 0);
    banded_attn_mfma_kernel<<<attn_g, 256, 0, stream>>>(QKV5, mask, Obf);
    global_attn_kernel<<<gl_g, 256, 0, stream>>>(QG0, QKV5, mask, Obf);
    gemm_bf16_kernel<<<gemm_g, 256, 0, stream>>>(Obf, wt + 5 * DD, bo + (size_t)l * D_,
                                                 Tb, nullptr, NROWS, D_, D_, 0);
    add_ln_kernel<<<NROWS, 256, 0, stream>>>(X, Tb, ln1_g + (size_t)l * D_,
                                             ln1_b + (size_t)l * D_, X, Xbf);
    gemm_bf16_kernel<<<ffn1_g, 256, 0, stream>>>(Xbf, wt + 6 * DD, b1 + (size_t)l * DFF_,
                                                 nullptr, Hbf, NROWS, DFF_, D_, 1);
    gemm_bf16_kernel<<<gemm_g, 256, 0, stream>>>(Hbf, wt + 6 * DD + DF,
                                                 b2 + (size_t)l * D_, Tb, nullptr,
                                                 NROWS, D_, DFF_, 0);
    add_ln_kernel<<<NROWS, 256, 0, stream>>>(X, Tb, ln2_g + (size_t)l * D_,
                                             ln2_b + (size_t)l * D_, X, Xbf);
  }
  skinny_kernel<<<sk_g, 256, 0, stream>>>(X, (size_t)S_ * D_, Wp, bp, pooled,
                                          D_, D_, 1.0f, 1);
  loss_kernel<<<1, 256, 0, stream>>>(pooled, Wfc, bfc, labels, (float*)d_out);
}